// Round 7
// baseline (334.315 us; speedup 1.0000x reference)
//
#include <hip/hip_runtime.h>
#include <hip/hip_bf16.h>

typedef __attribute__((ext_vector_type(8))) short short8;
typedef __attribute__((ext_vector_type(4))) float f32x4;

#define NTOK   100000
#define H      150
#define NFR    10         // 16-col fragments (160 padded cols)
#define NKS    20         // K-steps of 32 (4 segs x 5)
#define LROW   168        // bf16 elems per LDS row (336B): banks +20 mod 32 -> <=2-way (free)
#define OUTOFF (NTOK * H)

__device__ __forceinline__ unsigned short f2bf(float f) {
    unsigned int u = __builtin_bit_cast(unsigned int, f);
    u = (u + 0x7FFFu + ((u >> 16) & 1u)) >> 16;   // RNE
    return (unsigned short)u;
}

// ---------------------------------------------------------------------------
// Prepass: pack weights FRAGMENT-MAJOR so every B-frag load in the main
// kernel is 64 lanes x 16B = 1KB fully contiguous (ideal coalescing).
// wb[(((n*NKS + ks)*64 + lane)*8 + j] = W_seg[k2][col]
//   seg = ks/5, s5 = ks%5, col = n*16 + (lane&15), k2 = s5*32 + (lane>>4)*8 + j
// ---------------------------------------------------------------------------
__global__ void prep_w(const float* __restrict__ w_in, const float* __restrict__ w_out,
                       const float* __restrict__ u_in, const float* __restrict__ u_out,
                       unsigned short* __restrict__ wb) {
    int idx = blockIdx.x * 256 + threadIdx.x;
    if (idx >= NFR * NKS * 64 * 8) return;       // 102400 elems
    int j    = idx & 7;
    int lane = (idx >> 3) & 63;
    int ks   = (idx >> 9) % NKS;
    int n    = idx / (512 * NKS);
    int seg  = ks / 5, s5 = ks % 5;
    int col  = n * 16 + (lane & 15);
    int k2   = s5 * 32 + (lane >> 4) * 8 + j;
    float v = 0.0f;
    if (col < H && k2 < H) {
        const float* W = (seg == 0) ? w_in : (seg == 1) ? w_out : (seg == 2) ? u_in : u_out;
        v = W[k2 * H + col];
    }
    wb[idx] = f2bf(v);
}

// ---------------------------------------------------------------------------
// Main fused kernel. 4 waves/block, each wave owns 16 token rows x all 160
// output cols. Per segment (4): stage the wave's 16x150 fp32 X-slab (a
// CONTIGUOUS 9.6KB region -> lane-linear float2 loads) into wave-PRIVATE LDS
// as bf16, then 5 K-steps of {1 ds_read_b128 A-frag + 10 contiguous 1KB
// B-loads + 10 MFMA}. No __syncthreads anywhere.
// ---------------------------------------------------------------------------
__global__ __launch_bounds__(256, 4) void lstm_fused(
        const float* __restrict__ s_in, const float* __restrict__ s_out,
        const float* __restrict__ h_in, const float* __restrict__ h_out,
        const float* __restrict__ last_c, const unsigned short* __restrict__ wb,
        float* __restrict__ out) {
    __shared__ unsigned short Xs[4][16][LROW];   // 21504 B

    const int t    = threadIdx.x;
    const int lane = t & 63;
    const int wid  = t >> 6;
    const int lrow = lane & 15;   // A row in frag / B+C col in frag
    const int lko  = lane >> 4;   // k-group 0..3 / C row-group
    const int r0   = blockIdx.x * 64 + wid * 16;   // wave's first token row

    const float* Xseg[4] = {s_in, s_out, h_in, h_out};

    // zero the k-pad [150,160) once (10 elems = 5 u32 slots x 16 rows = 80)
#pragma unroll
    for (int it = 0; it < 2; it++) {
        int ss = lane + it * 64;
        if (ss < 80) {
            int row = ss / 5, c = ss % 5;
            *(unsigned int*)&Xs[wid][row][150 + 2 * c] = 0u;
        }
    }

    f32x4 acc[NFR];
#pragma unroll
    for (int n = 0; n < NFR; n++) acc[n] = (f32x4){0.f, 0.f, 0.f, 0.f};

    const bool tail = (r0 + 15 > NTOK - 1);   // only the last block

    for (int seg = 0; seg < 4; seg++) {
        const float* __restrict__ Xp = Xseg[seg];

        // ---- stage: 16 rows x 75 float2 slots = 1200, lane-linear ----
        if (!tail) {
            const float* __restrict__ Rp = Xp + (long)r0 * H;   // contiguous 9.6KB
#pragma unroll
            for (int it = 0; it < 19; it++) {
                int s = lane + it * 64;
                if (s < 1200) {
                    int row = s / 75, c2 = s - row * 75;
                    float2 v = *(const float2*)&Rp[s * 2];      // == row*150 + 2*c2
                    unsigned int p = (unsigned int)f2bf(v.x) | ((unsigned int)f2bf(v.y) << 16);
                    *(unsigned int*)&Xs[wid][row][2 * c2] = p;
                }
            }
        } else {
#pragma unroll
            for (int it = 0; it < 19; it++) {
                int s = lane + it * 64;
                if (s < 1200) {
                    int row = s / 75, c2 = s - row * 75;
                    int gr = r0 + row; if (gr > NTOK - 1) gr = NTOK - 1;
                    float2 v = *(const float2*)&Xp[(long)gr * H + 2 * c2];
                    unsigned int p = (unsigned int)f2bf(v.x) | ((unsigned int)f2bf(v.y) << 16);
                    *(unsigned int*)&Xs[wid][row][2 * c2] = p;
                }
            }
        }

        // wave-private LDS: DS ops are in-order per wave; fence compiler + HW
        asm volatile("s_waitcnt lgkmcnt(0)" ::: "memory");

        // ---- 5 K-steps ----
#pragma unroll
        for (int s5 = 0; s5 < 5; s5++) {
            const int ks = seg * 5 + s5;
            short8 bf[NFR];
#pragma unroll
            for (int n = 0; n < NFR; n++)
                bf[n] = *(const short8*)&wb[(((long)n * NKS + ks) * 64 + lane) * 8];
            short8 af = *(const short8*)&Xs[wid][lrow][s5 * 32 + lko * 8];
#pragma unroll
            for (int n = 0; n < NFR; n++)
                acc[n] = __builtin_amdgcn_mfma_f32_16x16x32_bf16(af, bf[n], acc[n], 0, 0, 0);
        }
    }

    // ---- fused epilogue: g = sigmoid(pre); cell = g*lc + g*g; hid = g*tanh(cell)
#pragma unroll
    for (int r = 0; r < 4; r++) {
        const int row = r0 + lko * 4 + r;
        if (row >= NTOK) continue;
        const long rb = (long)row * H;
#pragma unroll
        for (int n = 0; n < NFR; n++) {
            const int col = n * 16 + lrow;
            if (col >= H) continue;
            float pre = acc[n][r];
            float e   = __expf(-pre);
            float g   = __builtin_amdgcn_rcpf(1.f + e);
            float lc  = last_c[rb + col];
            float cell = g * lc + g * g;
            float e2  = __expf(-2.f * cell);
            float th  = (1.f - e2) * __builtin_amdgcn_rcpf(1.f + e2);
            out[rb + col]          = g * th;
            out[OUTOFF + rb + col] = cell;
        }
    }
}

extern "C" void kernel_launch(void* const* d_in, const int* in_sizes, int n_in,
                              void* d_out, int out_size, void* d_ws, size_t ws_size,
                              hipStream_t stream) {
    const float* s_in   = (const float*)d_in[0];
    const float* s_out  = (const float*)d_in[1];
    const float* h_in   = (const float*)d_in[2];
    const float* h_out  = (const float*)d_in[3];
    const float* last_c = (const float*)d_in[4];
    const float* w_in   = (const float*)d_in[5];
    const float* w_out  = (const float*)d_in[6];
    const float* u_in   = (const float*)d_in[7];
    const float* u_out  = (const float*)d_in[8];

    unsigned short* wb = (unsigned short*)d_ws;   // 102400*2 = 204800 B
    float* out = (float*)d_out;

    prep_w<<<(NFR * NKS * 64 * 8 + 255) / 256, 256, 0, stream>>>(w_in, w_out, u_in, u_out, wb);

    const int nblocks = (NTOK + 63) / 64;  // 1563 blocks, 4 waves, 16 rows/wave
    lstm_fused<<<nblocks, 256, 0, stream>>>(s_in, s_out, h_in, h_out, last_c, wb, out);
}

// Round 8
// 166.699 us; speedup vs baseline: 2.0055x; 2.0055x over previous
//
#include <hip/hip_runtime.h>
#include <hip/hip_bf16.h>

typedef __attribute__((ext_vector_type(8))) short short8;
typedef __attribute__((ext_vector_type(4))) float f32x4;

#define NTOK   100000
#define H      150
#define NFR    10         // 16-col fragments (160 padded cols)
#define NKS    20         // K-steps of 32 (4 segs x 5)
#define BM     64         // token rows per block
#define LROW   168        // bf16 elems per LDS row (336B): 84 mod 32 banks, period-8 -> conflict-free b128
#define NSLOT  (BM * 75)  // 4800 float2 staging slots per segment
#define OUTOFF (NTOK * H)

__device__ __forceinline__ unsigned short f2bf(float f) {
    unsigned int u = __builtin_bit_cast(unsigned int, f);
    u = (u + 0x7FFFu + ((u >> 16) & 1u)) >> 16;   // RNE
    return (unsigned short)u;
}

// ---------------------------------------------------------------------------
// Prepass: pack weights FRAGMENT-MAJOR so every B-frag load in the main
// kernel is 64 lanes x 16B = 1KB fully contiguous.
// wb[(((n*NKS + ks)*64 + lane)*8 + j] = W_seg[k2][col]
//   seg = ks/5, s5 = ks%5, col = n*16 + (lane&15), k2 = s5*32 + (lane>>4)*8 + j
// ---------------------------------------------------------------------------
__global__ void prep_w(const float* __restrict__ w_in, const float* __restrict__ w_out,
                       const float* __restrict__ u_in, const float* __restrict__ u_out,
                       unsigned short* __restrict__ wb) {
    int idx = blockIdx.x * 256 + threadIdx.x;
    if (idx >= NFR * NKS * 64 * 8) return;       // 102400 elems
    int j    = idx & 7;
    int lane = (idx >> 3) & 63;
    int ks   = (idx >> 9) % NKS;
    int n    = idx / (512 * NKS);
    int seg  = ks / 5, s5 = ks % 5;
    int col  = n * 16 + (lane & 15);
    int k2   = s5 * 32 + (lane >> 4) * 8 + j;
    float v = 0.0f;
    if (col < H && k2 < H) {
        const float* W = (seg == 0) ? w_in : (seg == 1) ? w_out : (seg == 2) ? u_in : u_out;
        v = W[k2 * H + col];
    }
    wb[idx] = f2bf(v);
}

// ---------------------------------------------------------------------------
// Main fused kernel. Block = 64 token rows x 160 cols; 4 waves, each wave
// owns 16 rows x all 160 cols. Double-buffered bf16 A-tiles in LDS; per
// segment: {ds_write prefetched slab -> barrier -> issue next slab's global
// loads -> 5 K-steps}. One barrier per segment; next slab's 38KB stays in
// flight under compute. B frags stream 1KB-contiguous from L2-resident wb.
// ---------------------------------------------------------------------------
__global__ __launch_bounds__(256, 3) void lstm_fused(
        const float* __restrict__ s_in, const float* __restrict__ s_out,
        const float* __restrict__ h_in, const float* __restrict__ h_out,
        const float* __restrict__ last_c, const unsigned short* __restrict__ wb,
        float* __restrict__ out) {
    __shared__ unsigned short Xs[2][BM][LROW];   // 43008 B -> 3 blocks/CU

    const int t     = threadIdx.x;
    const int lane  = t & 63;
    const int wid   = t >> 6;
    const int lrow  = lane & 15;   // A row in frag / B+C col in frag
    const int lko   = lane >> 4;   // k-group 0..3 / C row-group
    const int r0blk = blockIdx.x * BM;
    const int r0w   = r0blk + wid * 16;

    const float* Xseg[4] = {s_in, s_out, h_in, h_out};
    const bool tail = (r0blk + BM > NTOK);   // last block only

    // zero k-pad elems [150,160) of every row in BOTH buffers (read by MFMA,
    // never written by staging). 2 bufs x 64 rows x 5 u32 slots = 640.
    for (int i = t; i < 2 * BM * 5; i += 256) {
        int b = i / (BM * 5);
        int r = (i / 5) % BM;
        int c = i % 5;
        *(unsigned int*)&Xs[b][r][150 + 2 * c] = 0u;
    }

    f32x4 acc[NFR];
#pragma unroll
    for (int n = 0; n < NFR; n++) acc[n] = (f32x4){0.f, 0.f, 0.f, 0.f};

    // ---- prefetch registers: 19 float2 per thread covers 4800 slots ----
    float2 pf[19];

    // issue segment's global loads (lane-linear over the contiguous 38.4KB slab)
    auto issue = [&](int seg) {
        const float* __restrict__ Xp = Xseg[seg];
        if (!tail) {
            const float* __restrict__ Rp = Xp + (long)r0blk * H;
#pragma unroll
            for (int it = 0; it < 19; it++) {
                int s = t + it * 256;
                if (s < NSLOT) pf[it] = *(const float2*)&Rp[2 * s];   // 2s = row*150+2*c2
            }
        } else {
#pragma unroll
            for (int it = 0; it < 19; it++) {
                int s = t + it * 256;
                if (s < NSLOT) {
                    int row = s / 75, c2 = s - row * 75;
                    int gr = r0blk + row; if (gr > NTOK - 1) gr = NTOK - 1;
                    pf[it] = *(const float2*)&Xp[(long)gr * H + 2 * c2];
                }
            }
        }
    };

    issue(0);   // prologue

    for (int seg = 0; seg < 4; seg++) {
        // ---- convert + ds_write the slab prefetched for this segment ----
#pragma unroll
        for (int it = 0; it < 19; it++) {
            int s = t + it * 256;
            if (s < NSLOT) {
                int row = s / 75, c2 = s - row * 75;
                unsigned int p = (unsigned int)f2bf(pf[it].x)
                               | ((unsigned int)f2bf(pf[it].y) << 16);
                *(unsigned int*)&Xs[seg & 1][row][2 * c2] = p;
            }
        }
        __syncthreads();   // tile ready (also orders buffer reuse, see proof in notes)

        if (seg < 3) issue(seg + 1);   // next slab in flight under compute

        // ---- compute: 5 K-steps of {10 B-loads + 1 ds_read_b128 + 10 MFMA} ----
#pragma unroll
        for (int s5 = 0; s5 < 5; s5++) {
            const int ks = seg * 5 + s5;
            short8 bf[NFR];
#pragma unroll
            for (int n = 0; n < NFR; n++)
                bf[n] = *(const short8*)&wb[(((long)n * NKS + ks) * 64 + lane) * 8];
            short8 af = *(const short8*)&Xs[seg & 1][wid * 16 + lrow][s5 * 32 + lko * 8];
#pragma unroll
            for (int n = 0; n < NFR; n++)
                acc[n] = __builtin_amdgcn_mfma_f32_16x16x32_bf16(af, bf[n], acc[n], 0, 0, 0);
        }
    }

    // ---- fused epilogue: g = sigmoid(pre); cell = g*lc + g*g; hid = g*tanh(cell)
#pragma unroll
    for (int r = 0; r < 4; r++) {
        const int row = r0w + lko * 4 + r;
        if (row >= NTOK) continue;
        const long rb = (long)row * H;
#pragma unroll
        for (int n = 0; n < NFR; n++) {
            const int col = n * 16 + lrow;
            if (col >= H) continue;
            float pre = acc[n][r];
            float e   = __expf(-pre);
            float g   = __builtin_amdgcn_rcpf(1.f + e);
            float lc  = last_c[rb + col];
            float cell = g * lc + g * g;
            float e2  = __expf(-2.f * cell);
            float th  = (1.f - e2) * __builtin_amdgcn_rcpf(1.f + e2);
            out[rb + col]          = g * th;
            out[OUTOFF + rb + col] = cell;
        }
    }
}

extern "C" void kernel_launch(void* const* d_in, const int* in_sizes, int n_in,
                              void* d_out, int out_size, void* d_ws, size_t ws_size,
                              hipStream_t stream) {
    const float* s_in   = (const float*)d_in[0];
    const float* s_out  = (const float*)d_in[1];
    const float* h_in   = (const float*)d_in[2];
    const float* h_out  = (const float*)d_in[3];
    const float* last_c = (const float*)d_in[4];
    const float* w_in   = (const float*)d_in[5];
    const float* w_out  = (const float*)d_in[6];
    const float* u_in   = (const float*)d_in[7];
    const float* u_out  = (const float*)d_in[8];

    unsigned short* wb = (unsigned short*)d_ws;   // 102400*2 = 204800 B
    float* out = (float*)d_out;

    prep_w<<<(NFR * NKS * 64 * 8 + 255) / 256, 256, 0, stream>>>(w_in, w_out, u_in, u_out, wb);

    const int nblocks = (NTOK + BM - 1) / BM;  // 1563 blocks, 4 waves, 16 rows/wave
    lstm_fused<<<nblocks, 256, 0, stream>>>(s_in, s_out, h_in, h_out, last_c, wb, out);
}